// Round 1
// baseline (327.401 us; speedup 1.0000x reference)
//
#include <hip/hip_runtime.h>

#define NB0 24
#define NB1 12
#define NB2 16
#define NC_TOTAL (NB0 + NB1 + NB2)   // 52

struct KParams {
    float c[NC_TOTAL];   // bin centers, bit-exact vs JAX f32 compute
    float inv_w[3];      // n / (2*pi), only used for candidate localization
};

__device__ __forceinline__ float geo_dist(float a, float c, float two_pi) {
    // EXACT replication of reference: diff = |a - c|; dist = min(diff, 2pi - diff)
    // (sub / abs / sub / min: no mul+add pair, so no contraction hazard)
    float diff = fabsf(a - c);
    float alt  = two_pi - diff;
    return fminf(diff, alt);
}

template <int N>
__device__ __forceinline__ void quant1(float a, const float* __restrict__ sc,
                                       float inv_w, float pi_f, float two_pi,
                                       int& idx_out, float& q_out) {
    // Analytic containing bin (approximate arithmetic is fine here;
    // exactness comes from the candidate evaluation below).
    float u = (a + pi_f) * inv_w;
    int k = (int)floorf(u);
    k = (k < 0) ? 0 : ((k > N - 1) ? (N - 1) : k);
    int km = (k == 0) ? (N - 1) : (k - 1);
    int kp = (k == N - 1) ? 0 : (k + 1);

    // Evaluate the reference's computed distances at the 3 candidates.
    float dk = geo_dist(a, sc[k],  two_pi);
    float dm = geo_dist(a, sc[km], two_pi);
    float dp = geo_dist(a, sc[kp], two_pi);

    // argmin semantics: minimum distance, ties -> lowest index (first occurrence)
    int best = k; float bd = dk;
    if (dm < bd || (dm == bd && km < best)) { bd = dm; best = km; }
    if (dp < bd || (dp == bd && kp < best)) { bd = dp; best = kp; }

    idx_out = best;
    float t = sc[best] - a;   // replicate q = a + (c - a) with separate f32 ops
    q_out = a + t;
}

__global__ void __launch_bounds__(256) cyclicvq_kernel(
    const float* __restrict__ angles,
    const int*   __restrict__ mask,
    float* __restrict__ out_q,
    float* __restrict__ out_i,
    int nrows, KParams p)
{
    __shared__ float sc[NC_TOTAL];
    if (threadIdx.x < NC_TOTAL) sc[threadIdx.x] = p.c[threadIdx.x];
    __syncthreads();

    const float pi_f   = (float)3.141592653589793;
    const float two_pi = (float)6.283185307179586;

    int tid    = blockIdx.x * blockDim.x + threadIdx.x;
    int stride = gridDim.x * blockDim.x;
    int nquad  = nrows >> 2;

    for (int qi = tid; qi < nquad; qi += stride) {
        long long row0 = (long long)qi * 4;

        const float4* ap = (const float4*)(angles + row0 * 3);
        float4 av0 = ap[0], av1 = ap[1], av2 = ap[2];
        const int4* mp = (const int4*)(mask + row0 * 2);
        int4 mv0 = mp[0], mv1 = mp[1];

        float a[12] = {av0.x, av0.y, av0.z, av0.w,
                       av1.x, av1.y, av1.z, av1.w,
                       av2.x, av2.y, av2.z, av2.w};
        int m[8] = {mv0.x, mv0.y, mv0.z, mv0.w,
                    mv1.x, mv1.y, mv1.z, mv1.w};

        float qo[12], io[12];
        #pragma unroll
        for (int r = 0; r < 4; ++r) {
            float a0 = a[3*r], a1 = a[3*r+1], a2 = a[3*r+2];
            int i0, i1, i2; float q0, q1, q2;
            quant1<NB0>(a0, sc,             p.inv_w[0], pi_f, two_pi, i0, q0);
            quant1<NB1>(a1, sc + NB0,       p.inv_w[1], pi_f, two_pi, i1, q1);
            quant1<NB2>(a2, sc + NB0 + NB1, p.inv_w[2], pi_f, two_pi, i2, q2);
            bool mt = (m[2*r]     != 0);
            bool mr = (m[2*r + 1] != 0);
            qo[3*r]   = mt ? 0.0f : q0;
            qo[3*r+1] = mr ? 0.0f : q1;
            qo[3*r+2] = q2;
            io[3*r]   = mt ? (float)NB0 : (float)i0;
            io[3*r+1] = mr ? (float)NB1 : (float)i1;
            io[3*r+2] = (float)i2;
        }

        float4* oq = (float4*)(out_q + row0 * 3);
        oq[0] = make_float4(qo[0], qo[1], qo[2],  qo[3]);
        oq[1] = make_float4(qo[4], qo[5], qo[6],  qo[7]);
        oq[2] = make_float4(qo[8], qo[9], qo[10], qo[11]);
        float4* oi = (float4*)(out_i + row0 * 3);
        oi[0] = make_float4(io[0], io[1], io[2],  io[3]);
        oi[1] = make_float4(io[4], io[5], io[6],  io[7]);
        oi[2] = make_float4(io[8], io[9], io[10], io[11]);
    }

    // scalar tail (nrows not divisible by 4)
    for (int row = (nquad << 2) + tid; row < nrows; row += stride) {
        long long r3 = (long long)row * 3;
        long long r2 = (long long)row * 2;
        float a0 = angles[r3 + 0], a1 = angles[r3 + 1], a2 = angles[r3 + 2];
        int i0, i1, i2; float q0, q1, q2;
        quant1<NB0>(a0, sc,             p.inv_w[0], pi_f, two_pi, i0, q0);
        quant1<NB1>(a1, sc + NB0,       p.inv_w[1], pi_f, two_pi, i1, q1);
        quant1<NB2>(a2, sc + NB0 + NB1, p.inv_w[2], pi_f, two_pi, i2, q2);
        bool mt = (mask[r2 + 0] != 0);
        bool mr = (mask[r2 + 1] != 0);
        out_q[r3 + 0] = mt ? 0.0f : q0;
        out_q[r3 + 1] = mr ? 0.0f : q1;
        out_q[r3 + 2] = q2;
        out_i[r3 + 0] = mt ? (float)NB0 : (float)i0;
        out_i[r3 + 1] = mr ? (float)NB1 : (float)i1;
        out_i[r3 + 2] = (float)i2;
    }
}

static void fill_params(KParams& p) {
    const double PI_D = 3.141592653589793;
    const int nb[3] = {NB0, NB1, NB2};
    int off = 0;
    for (int d = 0; d < 3; ++d) {
        // Match JAX: w = f32(2*pi/n); c_k = f32(f32(-pi) + f32(w * (k + 0.5)))
        // volatile temporaries forbid host-side fma contraction.
        float w = (float)(2.0 * PI_D / (double)nb[d]);
        for (int k = 0; k < nb[d]; ++k) {
            volatile float t = w * ((float)k + 0.5f);
            volatile float c = (float)(-PI_D) + t;
            p.c[off + k] = c;
        }
        p.inv_w[d] = (float)((double)nb[d] / (2.0 * PI_D));
        off += nb[d];
    }
}

extern "C" void kernel_launch(void* const* d_in, const int* in_sizes, int n_in,
                              void* d_out, int out_size, void* d_ws, size_t ws_size,
                              hipStream_t stream) {
    const float* angles = (const float*)d_in[0];
    const int*   mask   = (const int*)d_in[1];
    float* out = (float*)d_out;

    const int total = in_sizes[0];      // nrows * 3
    const int nrows = total / 3;
    float* out_q = out;                 // quantized, flattened (nrows,3)
    float* out_i = out + total;         // indices as f32, flattened (nrows,3)

    KParams p;
    fill_params(p);

    int nquad  = nrows >> 2;
    int blocks = (nquad + 255) / 256;
    if (blocks > 2048) blocks = 2048;
    if (blocks < 1)    blocks = 1;

    hipLaunchKernelGGL(cyclicvq_kernel, dim3(blocks), dim3(256), 0, stream,
                       angles, mask, out_q, out_i, nrows, p);
}

// Round 3
// 325.907 us; speedup vs baseline: 1.0046x; 1.0046x over previous
//
#include <hip/hip_runtime.h>

typedef float v4f __attribute__((ext_vector_type(4)));
typedef int   v4i __attribute__((ext_vector_type(4)));

#define NB0 24
#define NB1 12
#define NB2 16
#define NC_TOTAL (NB0 + NB1 + NB2)   // 52

struct KParams {
    float c[NC_TOTAL];   // bin centers, host-computed — bit-exact vs JAX f32 (proven r1)
    float inv_w[3];      // n / (2*pi), only for candidate localization
};

// ---- numeric path: VERBATIM from round 1 (absmax == 0.0) — do not touch ----
__device__ __forceinline__ float geo_dist(float a, float c, float two_pi) {
    float diff = fabsf(a - c);
    float alt  = two_pi - diff;      // sub/abs/sub/min only: no contraction hazard
    return fminf(diff, alt);
}

template <int N>
__device__ __forceinline__ void quant1(float a, const float* __restrict__ sc,
                                       float inv_w, float pi_f, float two_pi,
                                       int& idx_out, float& q_out) {
    float u = (a + pi_f) * inv_w;    // approx localization; exactness from candidates
    int k = (int)floorf(u);
    k = (k < 0) ? 0 : ((k > N - 1) ? (N - 1) : k);
    int km = (k == 0) ? (N - 1) : (k - 1);
    int kp = (k == N - 1) ? 0 : (k + 1);

    float dk = geo_dist(a, sc[k],  two_pi);
    float dm = geo_dist(a, sc[km], two_pi);
    float dp = geo_dist(a, sc[kp], two_pi);

    // argmin semantics: min distance, ties -> lowest index (first occurrence)
    int best = k; float bd = dk;
    if (dm < bd || (dm == bd && km < best)) { bd = dm; best = km; }
    if (dp < bd || (dp == bd && kp < best)) { bd = dp; best = kp; }

    idx_out = best;
    float t = sc[best] - a;          // q = a + (c - a), separate f32 roundings (no mul)
    q_out = a + t;
}
// ---------------------------------------------------------------------------

__device__ __forceinline__ void do_row(const float* __restrict__ sc,
                                       float iw0, float iw1, float iw2,
                                       float pi_f, float two_pi,
                                       float a0, float a1, float a2, int mt_i, int mr_i,
                                       float& q0, float& q1, float& q2,
                                       float& i0, float& i1, float& i2) {
    int b0, b1, b2; float t0, t1, t2;
    quant1<NB0>(a0, sc,             iw0, pi_f, two_pi, b0, t0);
    quant1<NB1>(a1, sc + NB0,       iw1, pi_f, two_pi, b1, t1);
    quant1<NB2>(a2, sc + NB0 + NB1, iw2, pi_f, two_pi, b2, t2);
    bool mt = (mt_i != 0), mr = (mr_i != 0);
    q0 = mt ? 0.0f : t0;
    q1 = mr ? 0.0f : t1;
    q2 = t2;
    i0 = mt ? (float)NB0 : (float)b0;
    i1 = mr ? (float)NB1 : (float)b1;
    i2 = (float)b2;
}

__global__ void __launch_bounds__(256) cyclicvq_kernel(
    const float* __restrict__ angles,
    const int*   __restrict__ mask,
    float* __restrict__ out_q,
    float* __restrict__ out_i,
    int nrows, KParams p)
{
    __shared__ float sc[NC_TOTAL];
    if (threadIdx.x < NC_TOTAL) sc[threadIdx.x] = p.c[threadIdx.x];
    __syncthreads();

    const float pi_f   = (float)3.141592653589793;
    const float two_pi = (float)6.283185307179586;
    const float iw0 = p.inv_w[0], iw1 = p.inv_w[1], iw2 = p.inv_w[2];

    int tid    = blockIdx.x * blockDim.x + threadIdx.x;
    int stride = gridDim.x * blockDim.x;
    int nquad  = nrows >> 2;

    for (int qi = tid; qi < nquad; qi += stride) {
        long long row0 = (long long)qi * 4;

        const v4f* ap = (const v4f*)(angles + row0 * 3);
        v4f av0 = __builtin_nontemporal_load(ap + 0);
        v4f av1 = __builtin_nontemporal_load(ap + 1);
        v4f av2 = __builtin_nontemporal_load(ap + 2);
        const v4i* mp = (const v4i*)(mask + row0 * 2);
        v4i mv0 = __builtin_nontemporal_load(mp + 0);
        v4i mv1 = __builtin_nontemporal_load(mp + 1);

        // 4 rows, fully scalarized (no runtime-indexed arrays -> no scratch)
        float q00,q01,q02,i00,i01,i02;
        float q10,q11,q12,i10,i11,i12;
        float q20,q21,q22,i20,i21,i22;
        float q30,q31,q32,i30,i31,i32;
        do_row(sc, iw0,iw1,iw2, pi_f,two_pi, av0.x, av0.y, av0.z, mv0.x, mv0.y,
               q00,q01,q02, i00,i01,i02);
        do_row(sc, iw0,iw1,iw2, pi_f,two_pi, av0.w, av1.x, av1.y, mv0.z, mv0.w,
               q10,q11,q12, i10,i11,i12);
        do_row(sc, iw0,iw1,iw2, pi_f,two_pi, av1.z, av1.w, av2.x, mv1.x, mv1.y,
               q20,q21,q22, i20,i21,i22);
        do_row(sc, iw0,iw1,iw2, pi_f,two_pi, av2.y, av2.z, av2.w, mv1.z, mv1.w,
               q30,q31,q32, i30,i31,i32);

        v4f* oq = (v4f*)(out_q + row0 * 3);
        __builtin_nontemporal_store((v4f){q00,q01,q02,q10}, oq + 0);
        __builtin_nontemporal_store((v4f){q11,q12,q20,q21}, oq + 1);
        __builtin_nontemporal_store((v4f){q22,q30,q31,q32}, oq + 2);
        v4f* oi = (v4f*)(out_i + row0 * 3);
        __builtin_nontemporal_store((v4f){i00,i01,i02,i10}, oi + 0);
        __builtin_nontemporal_store((v4f){i11,i12,i20,i21}, oi + 1);
        __builtin_nontemporal_store((v4f){i22,i30,i31,i32}, oi + 2);
    }

    // scalar tail (nrows not divisible by 4)
    for (int row = (nquad << 2) + tid; row < nrows; row += stride) {
        long long r3 = (long long)row * 3;
        long long r2 = (long long)row * 2;
        float q0,q1,q2,i0,i1,i2;
        do_row(sc, iw0,iw1,iw2, pi_f,two_pi,
               angles[r3], angles[r3+1], angles[r3+2], mask[r2], mask[r2+1],
               q0,q1,q2, i0,i1,i2);
        out_q[r3+0] = q0; out_q[r3+1] = q1; out_q[r3+2] = q2;
        out_i[r3+0] = i0; out_i[r3+1] = i1; out_i[r3+2] = i2;
    }
}

// VERBATIM from round 1 (absmax == 0.0): two-step f32 rounding, volatile blocks fma
static void fill_params(KParams& p) {
    const double PI_D = 3.141592653589793;
    const int nb[3] = {NB0, NB1, NB2};
    int off = 0;
    for (int d = 0; d < 3; ++d) {
        float w = (float)(2.0 * PI_D / (double)nb[d]);
        for (int k = 0; k < nb[d]; ++k) {
            volatile float t = w * ((float)k + 0.5f);
            volatile float c = (float)(-PI_D) + t;
            p.c[off + k] = c;
        }
        p.inv_w[d] = (float)((double)nb[d] / (2.0 * PI_D));
        off += nb[d];
    }
}

extern "C" void kernel_launch(void* const* d_in, const int* in_sizes, int n_in,
                              void* d_out, int out_size, void* d_ws, size_t ws_size,
                              hipStream_t stream) {
    const float* angles = (const float*)d_in[0];
    const int*   mask   = (const int*)d_in[1];
    float* out = (float*)d_out;

    const int total = in_sizes[0];   // nrows * 3
    const int nrows = total / 3;
    float* out_q = out;              // quantized (nrows,3) f32
    float* out_i = out + total;      // indices (nrows,3), written as f32 values

    KParams p;
    fill_params(p);

    int nquad  = nrows >> 2;
    int blocks = (nquad + 255) / 256;   // exact fit: 8192 blocks for 4096x2048
    if (blocks < 1) blocks = 1;

    hipLaunchKernelGGL(cyclicvq_kernel, dim3(blocks), dim3(256), 0, stream,
                       angles, mask, out_q, out_i, nrows, p);
}

// Round 4
// 299.505 us; speedup vs baseline: 1.0931x; 1.0882x over previous
//
#include <hip/hip_runtime.h>

typedef float v4f __attribute__((ext_vector_type(4)));
typedef int   v4i __attribute__((ext_vector_type(4)));

#define NB0 24
#define NB1 12
#define NB2 16
#define NC_TOTAL (NB0 + NB1 + NB2)   // 52

struct KParams {
    float c[NC_TOTAL];   // bin centers, host-computed — bit-exact vs JAX f32 (proven r1/r3)
    float inv_w[3];
};

// ---- numeric path: VERBATIM from round 1/3 (absmax == 0.0) — do not touch ----
__device__ __forceinline__ float geo_dist(float a, float c, float two_pi) {
    float diff = fabsf(a - c);
    float alt  = two_pi - diff;
    return fminf(diff, alt);
}

template <int N>
__device__ __forceinline__ void quant1(float a, const float* __restrict__ sc,
                                       float inv_w, float pi_f, float two_pi,
                                       int& idx_out, float& q_out) {
    float u = (a + pi_f) * inv_w;
    int k = (int)floorf(u);
    k = (k < 0) ? 0 : ((k > N - 1) ? (N - 1) : k);
    int km = (k == 0) ? (N - 1) : (k - 1);
    int kp = (k == N - 1) ? 0 : (k + 1);

    float dk = geo_dist(a, sc[k],  two_pi);
    float dm = geo_dist(a, sc[km], two_pi);
    float dp = geo_dist(a, sc[kp], two_pi);

    int best = k; float bd = dk;
    if (dm < bd || (dm == bd && km < best)) { bd = dm; best = km; }
    if (dp < bd || (dp == bd && kp < best)) { bd = dp; best = kp; }

    idx_out = best;
    float t = sc[best] - a;
    q_out = a + t;
}

__device__ __forceinline__ void do_row(const float* __restrict__ sc,
                                       float iw0, float iw1, float iw2,
                                       float pi_f, float two_pi,
                                       float a0, float a1, float a2, int mt_i, int mr_i,
                                       float& q0, float& q1, float& q2,
                                       float& i0, float& i1, float& i2) {
    int b0, b1, b2; float t0, t1, t2;
    quant1<NB0>(a0, sc,             iw0, pi_f, two_pi, b0, t0);
    quant1<NB1>(a1, sc + NB0,       iw1, pi_f, two_pi, b1, t1);
    quant1<NB2>(a2, sc + NB0 + NB1, iw2, pi_f, two_pi, b2, t2);
    bool mt = (mt_i != 0), mr = (mr_i != 0);
    q0 = mt ? 0.0f : t0;
    q1 = mr ? 0.0f : t1;
    q2 = t2;
    i0 = mt ? (float)NB0 : (float)b0;
    i1 = mr ? (float)NB1 : (float)b1;
    i2 = (float)b2;
}
// ---------------------------------------------------------------------------

// Wave geometry: 64 lanes x 4 rows = 256 rows/wave; 4 waves/block = 1024 rows/block.
// Per-wave LDS region: 6144 B. Phase 1: A-stage (3072 B used). Phase 2: Q (3072) + I (3072).
// Q aliases A safely: lane x overwrites exactly the 48 B only lane x read.
#define WAVE_LDS 6144

__global__ void __launch_bounds__(256) cyclicvq_kernel(
    const float* __restrict__ angles,
    const int*   __restrict__ mask,
    float* __restrict__ out_q,
    float* __restrict__ out_i,
    int nrows, KParams p)
{
    __shared__ float sc[NC_TOTAL];
    __shared__ unsigned char smem[4 * WAVE_LDS];
    if (threadIdx.x < NC_TOTAL) sc[threadIdx.x] = p.c[threadIdx.x];

    const float pi_f   = (float)3.141592653589793;
    const float two_pi = (float)6.283185307179586;
    const float iw0 = p.inv_w[0], iw1 = p.inv_w[1], iw2 = p.inv_w[2];

    const int wave = threadIdx.x >> 6;
    const int lane = threadIdx.x & 63;
    const int block_row0 = blockIdx.x << 10;          // 1024 rows per block

    if (block_row0 + 1024 <= nrows) {
        // ---------------- fast path: fully coalesced via LDS transpose ----------------
        const int wave_row0 = block_row0 + (wave << 8);   // 256 rows per wave
        const int ga = (wave_row0 * 3) >> 2;              // float4 index into angles/outputs
        const int gm = (wave_row0 >> 1);                  // int4 index into mask

        const v4f* av = (const v4f*)angles;
        v4f A0 = __builtin_nontemporal_load(av + ga + lane);
        v4f A1 = __builtin_nontemporal_load(av + ga + 64 + lane);
        v4f A2 = __builtin_nontemporal_load(av + ga + 128 + lane);

        // masks: direct per-lane loads (32-B stride; minor traffic, skip staging)
        const v4i* mv = (const v4i*)mask;
        v4i M0 = __builtin_nontemporal_load(mv + gm + 2 * lane);
        v4i M1 = __builtin_nontemporal_load(mv + gm + 2 * lane + 1);

        unsigned char* wbase = smem + wave * WAVE_LDS;
        v4f* sA = (v4f*)wbase;                // 192 float4 = 768 floats
        sA[lane]       = A0;
        sA[64 + lane]  = A1;
        sA[128 + lane] = A2;
        __syncthreads();                      // stage visible (also covers sc table)

        // transposed read: lane owns rows wave_row0 + 4*lane .. +3  (floats 12*lane..+11)
        const float* fA = (const float*)wbase;
        v4f a0 = ((const v4f*)(fA + 12 * lane))[0];
        v4f a1 = ((const v4f*)(fA + 12 * lane))[1];
        v4f a2 = ((const v4f*)(fA + 12 * lane))[2];

        float q00,q01,q02,i00,i01,i02;
        float q10,q11,q12,i10,i11,i12;
        float q20,q21,q22,i20,i21,i22;
        float q30,q31,q32,i30,i31,i32;
        do_row(sc, iw0,iw1,iw2, pi_f,two_pi, a0.x, a0.y, a0.z, M0.x, M0.y,
               q00,q01,q02, i00,i01,i02);
        do_row(sc, iw0,iw1,iw2, pi_f,two_pi, a0.w, a1.x, a1.y, M0.z, M0.w,
               q10,q11,q12, i10,i11,i12);
        do_row(sc, iw0,iw1,iw2, pi_f,two_pi, a1.z, a1.w, a2.x, M1.x, M1.y,
               q20,q21,q22, i20,i21,i22);
        do_row(sc, iw0,iw1,iw2, pi_f,two_pi, a2.y, a2.z, a2.w, M1.z, M1.w,
               q30,q31,q32, i30,i31,i32);

        // strided LDS writes: lane x overwrites exactly its own read bytes (Q aliases A)
        float* fQ = (float*)wbase;
        float* fI = (float*)(wbase + 3072);
        ((v4f*)(fQ + 12 * lane))[0] = (v4f){q00,q01,q02,q10};
        ((v4f*)(fQ + 12 * lane))[1] = (v4f){q11,q12,q20,q21};
        ((v4f*)(fQ + 12 * lane))[2] = (v4f){q22,q30,q31,q32};
        ((v4f*)(fI + 12 * lane))[0] = (v4f){i00,i01,i02,i10};
        ((v4f*)(fI + 12 * lane))[1] = (v4f){i11,i12,i20,i21};
        ((v4f*)(fI + 12 * lane))[2] = (v4f){i22,i30,i31,i32};
        __syncthreads();

        // linear readback -> fully coalesced 1-KiB stores
        const v4f* sQ = (const v4f*)wbase;
        const v4f* sI = (const v4f*)(wbase + 3072);
        v4f* oq = (v4f*)out_q;
        v4f* oi = (v4f*)out_i;
        __builtin_nontemporal_store(sQ[lane],        oq + ga + lane);
        __builtin_nontemporal_store(sQ[64 + lane],   oq + ga + 64 + lane);
        __builtin_nontemporal_store(sQ[128 + lane],  oq + ga + 128 + lane);
        __builtin_nontemporal_store(sI[lane],        oi + ga + lane);
        __builtin_nontemporal_store(sI[64 + lane],   oi + ga + 64 + lane);
        __builtin_nontemporal_store(sI[128 + lane],  oi + ga + 128 + lane);
    } else {
        // ---------------- tail path: scalar, rarely taken (last partial block) --------
        __syncthreads();   // make sc visible
        for (int row = block_row0 + (int)threadIdx.x; row < nrows; row += 256) {
            long long r3 = (long long)row * 3;
            long long r2 = (long long)row * 2;
            float q0,q1,q2,i0,i1,i2;
            do_row(sc, iw0,iw1,iw2, pi_f,two_pi,
                   angles[r3], angles[r3+1], angles[r3+2], mask[r2], mask[r2+1],
                   q0,q1,q2, i0,i1,i2);
            out_q[r3+0] = q0; out_q[r3+1] = q1; out_q[r3+2] = q2;
            out_i[r3+0] = i0; out_i[r3+1] = i1; out_i[r3+2] = i2;
        }
    }
}

// VERBATIM from round 1/3 (absmax == 0.0): two-step f32 rounding, volatile blocks fma
static void fill_params(KParams& p) {
    const double PI_D = 3.141592653589793;
    const int nb[3] = {NB0, NB1, NB2};
    int off = 0;
    for (int d = 0; d < 3; ++d) {
        float w = (float)(2.0 * PI_D / (double)nb[d]);
        for (int k = 0; k < nb[d]; ++k) {
            volatile float t = w * ((float)k + 0.5f);
            volatile float c = (float)(-PI_D) + t;
            p.c[off + k] = c;
        }
        p.inv_w[d] = (float)((double)nb[d] / (2.0 * PI_D));
        off += nb[d];
    }
}

extern "C" void kernel_launch(void* const* d_in, const int* in_sizes, int n_in,
                              void* d_out, int out_size, void* d_ws, size_t ws_size,
                              hipStream_t stream) {
    const float* angles = (const float*)d_in[0];
    const int*   mask   = (const int*)d_in[1];
    float* out = (float*)d_out;

    const int total = in_sizes[0];   // nrows * 3
    const int nrows = total / 3;
    float* out_q = out;              // quantized (nrows,3) f32
    float* out_i = out + total;      // indices (nrows,3), written as f32 values

    KParams p;
    fill_params(p);

    int blocks = (nrows + 1023) / 1024;   // 8192 for 4096x2048
    if (blocks < 1) blocks = 1;

    hipLaunchKernelGGL(cyclicvq_kernel, dim3(blocks), dim3(256), 0, stream,
                       angles, mask, out_q, out_i, nrows, p);
}